// Round 1
// 482.428 us; speedup vs baseline: 1.0395x; 1.0395x over previous
//
#include <hip/hip_runtime.h>

// OU scan: x_s = c_s * x_{s-1} + sqrt(1-c_s^2) * z_s,  c_s = exp(-theta*dt_s)
// B=64, S=4096, D=256. float32. 3-pass chunked scan, latency-optimized:
//  - 256-thread blocks: 4 waves, each wave owns one chunk (4 consecutive chunks/block)
//  - explicit 8-deep software-pipelined prefetch (statically rotated regs, full unroll)
//  - K2 parallelized to 256 blocks + same prefetch pipeline
//  - nontemporal out stores + nt final z loads to keep z resident in L3 between passes

#define THETA 0.5f
constexpr int Bn = 64;
constexpr int Sn = 4096;
constexpr int Dn = 256;
constexpr int CHUNK = 64;           // rows per chunk
constexpr int NC = Sn / CHUNK;      // 64 chunks per batch
constexpr int WPB = 4;              // chunks (waves) per block
constexpr int NCB = NC / WPB;       // 16 block-columns per batch
constexpr int PF = 8;               // prefetch depth (rows in flight per lane)

typedef float f32x4 __attribute__((ext_vector_type(4)));

// ---------------- K1: per-chunk aggregates ----------------
// 256 threads = 4 waves; wave w handles chunk (blk%NCB)*4 + w. Lane owns 4 d's.
__global__ __launch_bounds__(256) void k_agg(
    const float* __restrict__ t,    // [B,S]
    const float* __restrict__ x0,   // [B,D]
    const float* __restrict__ z,    // [B,S,D]
    float* __restrict__ agg)        // [B,NC,D]
{
    const int w    = threadIdx.x >> 6;
    const int lane = threadIdx.x & 63;
    const int b    = blockIdx.x / NCB;
    const int k    = (blockIdx.x % NCB) * WPB + w;
    const int s0   = k * CHUNK;

    __shared__ float2 css[WPB][CHUNK];
    {
        const int r = s0 + lane;
        const float tcur  = t[b * Sn + r];
        const float tprev = (r == 0) ? 0.0f : t[b * Sn + r - 1];
        const float c = __expf(-THETA * (tcur - tprev));
        css[w][lane] = make_float2(c, sqrtf(fmaxf(0.0f, 1.0f - c * c)));
    }
    __syncthreads();

    const int d0 = lane * 4;
    float a0 = 0.f, a1 = 0.f, a2 = 0.f, a3 = 0.f;
    if (k == 0) {
        const f32x4 xv = *(const f32x4*)(x0 + (size_t)b * Dn + d0);
        a0 = xv.x; a1 = xv.y; a2 = xv.z; a3 = xv.w;
    }

    const float* zp = z + ((size_t)b * Sn + s0) * Dn + d0;
    f32x4 buf[PF];   // statically indexed after full unroll -> stays in VGPRs
#pragma unroll
    for (int i = 0; i < PF; ++i)
        buf[i] = *(const f32x4*)(zp + (size_t)i * Dn);
#pragma unroll
    for (int r = 0; r < CHUNK; ++r) {
        const f32x4 zv = buf[r & (PF - 1)];
        if (r + PF < CHUNK)
            buf[r & (PF - 1)] = *(const f32x4*)(zp + (size_t)(r + PF) * Dn);
        const float2 cv = css[w][r];        // wave-uniform broadcast, conflict-free
        a0 = fmaf(cv.x, a0, cv.y * zv.x);
        a1 = fmaf(cv.x, a1, cv.y * zv.y);
        a2 = fmaf(cv.x, a2, cv.y * zv.z);
        a3 = fmaf(cv.x, a3, cv.y * zv.w);
    }

    f32x4 av; av.x = a0; av.y = a1; av.z = a2; av.w = a3;
    *(f32x4*)(agg + ((size_t)b * NC + k) * Dn + d0) = av;
}

// ---------------- K2: scan chunk aggregates -> exclusive carry-in (in place) --
// 256 blocks: b = blk/4, d-tile = blk%4 (64 d's per block). Prefetched chain.
__global__ __launch_bounds__(64) void k_scan(
    const float* __restrict__ t,
    float* __restrict__ agg)
{
    const int b    = blockIdx.x >> 2;
    const int tile = blockIdx.x & 3;
    const int lane = threadIdx.x;
    const int d    = tile * 64 + lane;

    __shared__ float As[NC];
    {
        const float tend = t[b * Sn + lane * CHUNK + CHUNK - 1];
        const float tpe  = (lane == 0) ? 0.0f : t[b * Sn + lane * CHUNK - 1];
        As[lane] = __expf(-THETA * (tend - tpe));
    }
    __syncthreads();

    float* ap = agg + (size_t)b * NC * Dn + d;
    float cin = 0.0f;
    float buf[PF];
#pragma unroll
    for (int i = 0; i < PF; ++i) buf[i] = ap[(size_t)i * Dn];
#pragma unroll
    for (int k = 0; k < NC; ++k) {
        const float bk = buf[k & (PF - 1)];
        if (k + PF < NC) buf[k & (PF - 1)] = ap[(size_t)(k + PF) * Dn];
        ap[(size_t)k * Dn] = cin;          // exclusive: carry INTO chunk k
        cin = fmaf(As[k], cin, bk);
    }
}

// ---------------- K3: apply carries, write output ----------------
__global__ __launch_bounds__(256) void k_final(
    const float* __restrict__ t,
    const float* __restrict__ x0,
    const float* __restrict__ z,
    const float* __restrict__ carry,   // [B,NC,D]
    float* __restrict__ out)           // [B,S,D]
{
    const int w    = threadIdx.x >> 6;
    const int lane = threadIdx.x & 63;
    const int b    = blockIdx.x / NCB;
    const int k    = (blockIdx.x % NCB) * WPB + w;
    const int s0   = k * CHUNK;

    __shared__ float2 css[WPB][CHUNK];
    {
        const int r = s0 + lane;
        const float tcur  = t[b * Sn + r];
        const float tprev = (r == 0) ? 0.0f : t[b * Sn + r - 1];
        const float c = __expf(-THETA * (tcur - tprev));
        css[w][lane] = make_float2(c, sqrtf(fmaxf(0.0f, 1.0f - c * c)));
    }
    __syncthreads();

    const int d0 = lane * 4;
    float a0, a1, a2, a3;
    if (k == 0) {
        const f32x4 xv = *(const f32x4*)(x0 + (size_t)b * Dn + d0);
        a0 = xv.x; a1 = xv.y; a2 = xv.z; a3 = xv.w;
    } else {
        const f32x4 cv = *(const f32x4*)(carry + ((size_t)b * NC + k) * Dn + d0);
        a0 = cv.x; a1 = cv.y; a2 = cv.z; a3 = cv.w;
    }

    const float* zp = z + ((size_t)b * Sn + s0) * Dn + d0;
    float* op = out + ((size_t)b * Sn + s0) * Dn + d0;

    f32x4 buf[PF];
#pragma unroll
    for (int i = 0; i < PF; ++i)
        buf[i] = __builtin_nontemporal_load((const f32x4*)(zp + (size_t)i * Dn));
#pragma unroll
    for (int r = 0; r < CHUNK; ++r) {
        const f32x4 zv = buf[r & (PF - 1)];
        if (r + PF < CHUNK)
            buf[r & (PF - 1)] =
                __builtin_nontemporal_load((const f32x4*)(zp + (size_t)(r + PF) * Dn));
        const float2 cv = css[w][r];
        a0 = fmaf(cv.x, a0, cv.y * zv.x);
        a1 = fmaf(cv.x, a1, cv.y * zv.y);
        a2 = fmaf(cv.x, a2, cv.y * zv.z);
        a3 = fmaf(cv.x, a3, cv.y * zv.w);
        f32x4 ov; ov.x = a0; ov.y = a1; ov.z = a2; ov.w = a3;
        __builtin_nontemporal_store(ov, (f32x4*)(op + (size_t)r * Dn));
    }
}

extern "C" void kernel_launch(void* const* d_in, const int* in_sizes, int n_in,
                              void* d_out, int out_size, void* d_ws, size_t ws_size,
                              hipStream_t stream) {
    const float* t  = (const float*)d_in[0];   // [B,S,1] f32
    const float* x0 = (const float*)d_in[1];   // [B,1,D] f32
    const float* z  = (const float*)d_in[2];   // [B,S,D] f32
    float* out = (float*)d_out;                // [B,S,D] f32

    float* agg = (float*)d_ws;   // [B,NC,D] = 4 MB: aggregates, then carry-ins

    k_agg  <<<Bn * NCB, 256, 0, stream>>>(t, x0, z, agg);
    k_scan <<<Bn * 4,    64, 0, stream>>>(t, agg);
    k_final<<<Bn * NCB, 256, 0, stream>>>(t, x0, z, agg, out);
}